// Round 1
// 547.570 us; speedup vs baseline: 1.0413x; 1.0413x over previous
//
#include <hip/hip_runtime.h>
#include <hip/hip_bf16.h>
#include <math.h>

#define LOG2E 1.4426950408889634f

typedef __attribute__((ext_vector_type(8))) short short8_t;
typedef __attribute__((ext_vector_type(4))) float float4_t;

union Frag { short8_t f; unsigned u[4]; };

__device__ inline unsigned pack_bf16(float lo, float hi){
  union { __hip_bfloat162 h2; unsigned u; } cv;
  cv.h2 = __float22bfloat162_rn(make_float2(lo, hi));
  return cv.u;
}

// ---------------- K1: 1x1 convs, 4-way output split for parallelism.
// qs: [b][n][8] fp32 (log2e folded); kk: [b][8][n] fp32; vT: [b][64][n] bf16.
__global__ __launch_bounds__(256) void k1_qkv(
    const float* __restrict__ x, const float* __restrict__ wq, const float* __restrict__ bq,
    const float* __restrict__ wk, const float* __restrict__ bk,
    const float* __restrict__ wv, const float* __restrict__ bv,
    float* __restrict__ qs, float* __restrict__ kk, unsigned short* __restrict__ vT,
    float* __restrict__ regout)
{
  int tid = blockIdx.x*256 + threadIdx.x;   // 65536 threads
  if (tid == 0) regout[0] = 0.f;            // reg output: amap is analytically constant
  int g = tid >> 14;                        // output group 0..3 (uniform per block)
  int p = tid & 16383;
  int b = p >> 12, n = p & 4095;
  const float* xp = x + (size_t)b*64*4096 + n;
  float xr[64];
  #pragma unroll
  for (int c=0;c<64;++c) xr[c] = xp[(size_t)c*4096];

  if (g == 0){
    float* qp = qs + ((size_t)b*4096 + n)*8;
    #pragma unroll
    for (int u=0;u<8;++u){
      const float* wr = wq + u*64;
      float a0=0,a1=0,a2=0,a3=0;
      #pragma unroll
      for (int c=0;c<64;c+=4){ a0=fmaf(wr[c],xr[c],a0); a1=fmaf(wr[c+1],xr[c+1],a1);
                               a2=fmaf(wr[c+2],xr[c+2],a2); a3=fmaf(wr[c+3],xr[c+3],a3); }
      qp[u] = (bq[u] + ((a0+a1)+(a2+a3))) * LOG2E;
    }
    #pragma unroll
    for (int u=0;u<8;++u){
      const float* wr = wk + u*64;
      float a0=0,a1=0,a2=0,a3=0;
      #pragma unroll
      for (int c=0;c<64;c+=4){ a0=fmaf(wr[c],xr[c],a0); a1=fmaf(wr[c+1],xr[c+1],a1);
                               a2=fmaf(wr[c+2],xr[c+2],a2); a3=fmaf(wr[c+3],xr[c+3],a3); }
      kk[((size_t)b*8+u)*4096 + n] = bk[u] + ((a0+a1)+(a2+a3));
    }
  } else {
    int c0 = (g==1) ? 0 : (g==2) ? 22 : 43;
    int c1 = (g==1) ? 22 : (g==2) ? 43 : 64;
    for (int u=c0; u<c1; ++u){
      const float* wr = wv + u*64;
      float a0=0,a1=0,a2=0,a3=0;
      #pragma unroll
      for (int c=0;c<64;c+=4){ a0=fmaf(wr[c],xr[c],a0); a1=fmaf(wr[c+1],xr[c+1],a1);
                               a2=fmaf(wr[c+2],xr[c+2],a2); a3=fmaf(wr[c+3],xr[c+3],a3); }
      float res = bv[u] + ((a0+a1)+(a2+a3));
      __hip_bfloat16 h = __float2bfloat16(res);
      vT[((size_t)b*64+u)*4096 + n] = *(unsigned short*)&h;
    }
  }
}

// ---------------- K3: fully fused. Block = 512 thr = 8 waves; 16 rows/block,
// each wave owns a 512-wide j-slice. Grid stays 1024 -> 4 blocks/CU x 8 waves
// = 32 waves/CU (was 16: grid-capped occupancy was the bottleneck).
// NO barriers / NO LDS in the j-loops: P is computed directly in MFMA A-frag
// layout (m=lane&15, k=q4*8+jj), B-frag is a contiguous ushort8 load from vT[c][j].
__global__ __launch_bounds__(512, 8) void k3_fused(
    const float* __restrict__ qs, const float* __restrict__ kk,
    const unsigned short* __restrict__ vT, const float* __restrict__ noise,
    const float* __restrict__ fwp, float* __restrict__ out)
{
  __shared__ float lds_l[8][16];
  __shared__ float lds_acc[8][16][64];
  int bid = blockIdx.x;                 // 1024 blocks: b = bid>>8, 16 rows each
  int b = bid >> 8; int i0 = (bid & 255) * 16;
  int t = threadIdx.x; int w = t >> 6; int lane = t & 63;
  int li = lane & 15, q4 = lane >> 4;
  int row = i0 + li;
  int jbase = w * 512;

  const float* qp = qs + ((size_t)b*4096 + row)*8;
  float qv[8];
  #pragma unroll
  for (int c=0;c<8;++c) qv[c] = qp[c];
  const float* kkb = kk + (size_t)b*8*4096;
  const float* nzr = noise + ((size_t)b*4096 + row)*4096;
  const unsigned short* vTb = vT + (size_t)b*64*4096;

  // ---- pass A: l1 over this wave's j-slice
  float l1 = 0.f;
  for (int sc=0; sc<16; ++sc){
    int j0 = jbase + sc*32 + q4*8;
    float s0=0,s1=0,s2=0,s3=0,s4=0,s5=0,s6=0,s7=0;
    #pragma unroll
    for (int c=0;c<8;++c){
      const float4* kp = (const float4*)(kkb + (size_t)c*4096 + j0);
      float4 ka = kp[0], kb2 = kp[1];
      float q = qv[c];
      s0=fmaf(q,ka.x,s0); s1=fmaf(q,ka.y,s1); s2=fmaf(q,ka.z,s2); s3=fmaf(q,ka.w,s3);
      s4=fmaf(q,kb2.x,s4); s5=fmaf(q,kb2.y,s5); s6=fmaf(q,kb2.z,s6); s7=fmaf(q,kb2.w,s7);
    }
    l1 += exp2f(s0-25.f); l1 += exp2f(s1-25.f); l1 += exp2f(s2-25.f); l1 += exp2f(s3-25.f);
    l1 += exp2f(s4-25.f); l1 += exp2f(s5-25.f); l1 += exp2f(s6-25.f); l1 += exp2f(s7-25.f);
  }
  l1 += __shfl_xor(l1, 16); l1 += __shfl_xor(l1, 32);
  if (lane < 16) lds_l[w][li] = l1;
  __syncthreads();
  float l1tot = 0.f;
  #pragma unroll
  for (int ww=0; ww<8; ++ww) l1tot += lds_l[ww][li];
  float c1 = LOG2E / l1tot;
  float ncoef = 0.1f * fwp[0] * LOG2E;

  // ---- pass B: p = exp2(e1*c1 + ncoef*noise - 2); PV via MFMA; l2 per row
  float4_t acc0 = {0.f,0.f,0.f,0.f}, acc1 = acc0, acc2 = acc0, acc3 = acc0;
  float l2 = 0.f;
  for (int sc=0; sc<16; ++sc){
    int j0 = jbase + sc*32 + q4*8;
    float s0=0,s1=0,s2=0,s3=0,s4=0,s5=0,s6=0,s7=0;
    #pragma unroll
    for (int c=0;c<8;++c){
      const float4* kp = (const float4*)(kkb + (size_t)c*4096 + j0);
      float4 ka = kp[0], kb2 = kp[1];
      float q = qv[c];
      s0=fmaf(q,ka.x,s0); s1=fmaf(q,ka.y,s1); s2=fmaf(q,ka.z,s2); s3=fmaf(q,ka.w,s3);
      s4=fmaf(q,kb2.x,s4); s5=fmaf(q,kb2.y,s5); s6=fmaf(q,kb2.z,s6); s7=fmaf(q,kb2.w,s7);
    }
    const float4* np = (const float4*)(nzr + j0);
    float4 n0 = np[0], n1 = np[1];
    float p0,p1,p2,p3,p4,p5,p6,p7;
    p0 = exp2f(fmaf(ncoef,n0.x, fmaf(exp2f(s0-25.f), c1, -2.f)));
    p1 = exp2f(fmaf(ncoef,n0.y, fmaf(exp2f(s1-25.f), c1, -2.f)));
    p2 = exp2f(fmaf(ncoef,n0.z, fmaf(exp2f(s2-25.f), c1, -2.f)));
    p3 = exp2f(fmaf(ncoef,n0.w, fmaf(exp2f(s3-25.f), c1, -2.f)));
    p4 = exp2f(fmaf(ncoef,n1.x, fmaf(exp2f(s4-25.f), c1, -2.f)));
    p5 = exp2f(fmaf(ncoef,n1.y, fmaf(exp2f(s5-25.f), c1, -2.f)));
    p6 = exp2f(fmaf(ncoef,n1.z, fmaf(exp2f(s6-25.f), c1, -2.f)));
    p7 = exp2f(fmaf(ncoef,n1.w, fmaf(exp2f(s7-25.f), c1, -2.f)));
    l2 += ((p0+p1)+(p2+p3)) + ((p4+p5)+(p6+p7));
    Frag af;
    af.u[0] = pack_bf16(p0,p1); af.u[1] = pack_bf16(p2,p3);
    af.u[2] = pack_bf16(p4,p5); af.u[3] = pack_bf16(p6,p7);
    const unsigned short* vp = vTb + (size_t)li*4096 + j0;
    short8_t b0 = *(const short8_t*)(vp);
    short8_t b1 = *(const short8_t*)(vp + 16*4096);
    short8_t b2 = *(const short8_t*)(vp + 32*4096);
    short8_t b3 = *(const short8_t*)(vp + 48*4096);
    acc0 = __builtin_amdgcn_mfma_f32_16x16x32_bf16(af.f, b0, acc0, 0, 0, 0);
    acc1 = __builtin_amdgcn_mfma_f32_16x16x32_bf16(af.f, b1, acc1, 0, 0, 0);
    acc2 = __builtin_amdgcn_mfma_f32_16x16x32_bf16(af.f, b2, acc2, 0, 0, 0);
    acc3 = __builtin_amdgcn_mfma_f32_16x16x32_bf16(af.f, b3, acc3, 0, 0, 0);
  }
  l2 += __shfl_xor(l2, 16); l2 += __shfl_xor(l2, 32);
  __syncthreads();                       // all waves done reading lds_l(l1)
  if (lane < 16) lds_l[w][li] = l2;
  // acc C/D layout: lane holds D[row=q4*4+reg][col=li]; col is the c-index tile
  #pragma unroll
  for (int reg=0; reg<4; ++reg){
    int rr = q4*4 + reg;
    lds_acc[w][rr][ 0 + li] = acc0[reg];
    lds_acc[w][rr][16 + li] = acc1[reg];
    lds_acc[w][rr][32 + li] = acc2[reg];
    lds_acc[w][rr][48 + li] = acc3[reg];
  }
  __syncthreads();
  // merge 8 j-slices + scale by 1/l2, write out[b][c][i0..i0+15]
  if (t < 256){
    int c = t >> 2, rg = t & 3;          // thread: one c, 4 consecutive rows
    float4 o;
    float* op = (float*)&o;
    #pragma unroll
    for (int r=0;r<4;++r){
      int rr = rg*4 + r;
      float vsum = 0.f, l2t = 0.f;
      #pragma unroll
      for (int ww=0; ww<8; ++ww){ vsum += lds_acc[ww][rr][c]; l2t += lds_l[ww][rr]; }
      op[r] = vsum / l2t;
    }
    *(float4*)(out + ((size_t)b*64 + c)*4096 + i0 + rg*4) = o;
  }
}

extern "C" void kernel_launch(void* const* d_in, const int* in_sizes, int n_in,
                              void* d_out, int out_size, void* d_ws, size_t ws_size,
                              hipStream_t stream) {
  const float* x     = (const float*)d_in[0];
  const float* wq    = (const float*)d_in[1];
  const float* bq    = (const float*)d_in[2];
  const float* wk    = (const float*)d_in[3];
  const float* bk    = (const float*)d_in[4];
  const float* wv    = (const float*)d_in[5];
  const float* bv    = (const float*)d_in[6];
  const float* fw    = (const float*)d_in[7];
  const float* noise = (const float*)d_in[8];
  float* out = (float*)d_out;
  float* ws  = (float*)d_ws;
  // scratch (floats): qs 131072 | kk 131072 | vT 524288 (1M ushort)
  float* qs = ws;
  float* kk = ws + 131072;
  unsigned short* vT = (unsigned short*)(ws + 262144);

  hipLaunchKernelGGL(k1_qkv,   dim3(256),  dim3(256), 0, stream,
                     x,wq,bq,wk,bk,wv,bv,qs,kk,vT, out + 1048576);
  hipLaunchKernelGGL(k3_fused, dim3(1024), dim3(512), 0, stream,
                     qs,kk,vT,noise,fw,out);
}